// Round 4
// baseline (260.165 us; speedup 1.0000x reference)
//
#include <hip/hip_runtime.h>
#include <math.h>

#define CONF_T 0.05f
#define NEGF  -1e10f
#define NCLS 16
#define TDET 100
#define CAP 4096
#define MTOT (NCLS*TDET)  // 1600

// pack (score, j) -> u64 so that umax == (max score, tie -> min j)
__device__ __forceinline__ unsigned long long packkey(float s, int j) {
  unsigned int b = __float_as_uint(s);
  b = (b & 0x80000000u) ? ~b : (b | 0x80000000u);   // total order for floats
  return ((unsigned long long)b << 32) | (unsigned int)(~j);
}
__device__ __forceinline__ float unpack_score(unsigned long long k) {
  unsigned int h = (unsigned int)(k >> 32);
  unsigned int b = (h & 0x80000000u) ? (h & 0x7fffffffu) : ~h;
  return __uint_as_float(b);
}

// ---------------- K1: decode boxes + class/score + per-chunk class counts ----------------
__global__ __launch_bounds__(256) void k_decode(
    const float* __restrict__ pred, const float* __restrict__ anch,
    float* __restrict__ boxes, float* __restrict__ score, int* __restrict__ cls,
    int* __restrict__ counts, int N, int nchunk)
{
  #pragma clang fp contract(off)
  const int b = blockIdx.x / nchunk;
  const int chunk = blockIdx.x % nchunk;
  const int t = threadIdx.x;
  const int n = chunk * 256 + t;

  __shared__ int hist[NCLS];
  if (t < NCLS) hist[t] = 0;
  __syncthreads();

  int v = -1;
  if (n < N) {
    const size_t i = (size_t)b * N + n;
    const float4* p4 = reinterpret_cast<const float4*>(pred + i * 20);
    float4 v0 = p4[0], v1 = p4[1], v2 = p4[2], v3 = p4[3], v4 = p4[4];
    float4 a = reinterpret_cast<const float4*>(anch)[n];  // cx, cy, w, h
    float xx = v0.x * a.z + a.x;
    float yy = v0.y * a.w + a.y;
    float wx = expf(v0.z) * a.z;
    float wy = expf(v0.w) * a.w;
    float hx = 0.5f * wx, hy = 0.5f * wy;
    float4 bx;
    bx.x = xx - hx; bx.y = yy - hy; bx.z = xx + hx; bx.w = yy + hy;
    reinterpret_cast<float4*>(boxes)[i] = bx;

    float lg[NCLS] = {v1.x, v1.y, v1.z, v1.w, v2.x, v2.y, v2.z, v2.w,
                      v3.x, v3.y, v3.z, v3.w, v4.x, v4.y, v4.z, v4.w};
    float best = -1.0f; int bi = 0;
    #pragma unroll
    for (int c = 0; c < NCLS; ++c) {
      float s = 1.0f / (1.0f + expf(-lg[c]));
      if (s > best) { best = s; bi = c; }
    }
    score[i] = best;
    v = (best >= CONF_T) ? bi : -1;
    cls[i] = v;
  }

  int lane = t & 63;
  #pragma unroll
  for (int c = 0; c < NCLS; ++c) {
    unsigned long long bl = __ballot(v == c);
    if (lane == 0 && bl) atomicAdd(&hist[c], __popcll(bl));
  }
  __syncthreads();
  if (t < NCLS) counts[(b * NCLS + t) * nchunk + chunk] = hist[t];
}

// ---------------- K2: per-(b,c) exclusive scan over chunk counts ----------------
__global__ __launch_bounds__(256) void k_scan(
    const int* __restrict__ counts, int* __restrict__ offs, int* __restrict__ ktot,
    int nchunk)
{
  const int bc = blockIdx.x;
  const int t = threadIdx.x;
  __shared__ int c_[256];
  __shared__ int o_[257];
  if (t < nchunk) c_[t] = counts[bc * nchunk + t];
  __syncthreads();
  if (t == 0) {
    int run = 0;
    for (int i = 0; i < nchunk; ++i) { o_[i] = run; run += c_[i]; }
    o_[nchunk] = run;
  }
  __syncthreads();
  if (t < nchunk) offs[bc * nchunk + t] = o_[t];
  if (t == 0) ktot[bc] = o_[nchunk];
}

// ---------------- K3: stable parallel scatter into per-(b,c) candidate lists ----------------
__global__ __launch_bounds__(256) void k_scatter(
    const float* __restrict__ score, const int* __restrict__ cls,
    const float* __restrict__ boxes, const int* __restrict__ offs,
    float* __restrict__ cand_sc, float* __restrict__ cand_bx,
    int N, int nchunk)
{
  const int b = blockIdx.x / nchunk;
  const int chunk = blockIdx.x % nchunk;
  const int t = threadIdx.x;
  const int n = chunk * 256 + t;

  __shared__ int wcnt[4][NCLS];
  int v = (n < N) ? cls[(size_t)b * N + n] : -1;
  int lane = t & 63, w = t >> 6;
  int myrank = 0;
  #pragma unroll
  for (int c = 0; c < NCLS; ++c) {
    unsigned long long bl = __ballot(v == c);
    if (lane == 0) wcnt[w][c] = __popcll(bl);
    if (v == c) myrank = __popcll(bl & ((1ull << lane) - 1ull));
  }
  __syncthreads();
  if (v >= 0) {
    int pre = 0;
    #pragma unroll
    for (int i = 0; i < 4; ++i) if (i < w) pre += wcnt[i][v];
    int pos = offs[(b * NCLS + v) * nchunk + chunk] + pre + myrank;
    if (pos < CAP) {
      int bc = b * NCLS + v;
      cand_sc[(size_t)bc * CAP + pos] = score[(size_t)b * N + n];
      reinterpret_cast<float4*>(cand_bx)[(size_t)bc * CAP + pos] =
          reinterpret_cast<const float4*>(boxes)[(size_t)b * N + n];
    }
  }
}

// ---------------- K4: per-(b,c) soft-NMS, 1024 threads, ONE barrier/iter ----------------
__global__ __launch_bounds__(1024) void k_nms(
    const float* __restrict__ cand_sc, const float* __restrict__ cand_bx,
    const int* __restrict__ ktot,
    float* __restrict__ out_box, float* __restrict__ out_sc, int* __restrict__ out_pick)
{
  #pragma clang fp contract(off)
  const int bc = blockIdx.x;
  const int t = threadIdx.x;
  const int lane = t & 63, w = t >> 6;

  __shared__ float4 s_box[CAP];                 // 64 KB: all candidate boxes
  __shared__ unsigned long long s_key[2][16];   // double-buffered wave keys

  int K = ktot[bc]; if (K > CAP) K = CAP;

  float  rsc[4];
  float4 rbx[4];
  float  rar[4];
  #pragma unroll
  for (int k = 0; k < 4; ++k) {
    int j = k * 1024 + t;
    if (j < K) {
      rsc[k] = cand_sc[(size_t)bc * CAP + j];
      float4 bb = reinterpret_cast<const float4*>(cand_bx)[(size_t)bc * CAP + j];
      rbx[k] = bb;
      s_box[j] = bb;
      rar[k] = (bb.z - bb.x) * (bb.w - bb.y);   // hoisted areaB (value-identical)
    } else {
      rsc[k] = NEGF;
      rbx[k].x = rbx[k].y = rbx[k].z = rbx[k].w = 0.0f;
      rar[k] = 0.0f;
    }
  }

  // pre-loop: local argmax + wave butterfly -> s_key[0][w]
  {
    float bs = rsc[0]; int bk = 0;
    #pragma unroll
    for (int k = 1; k < 4; ++k)
      if (rsc[k] > bs) { bs = rsc[k]; bk = k; }
    unsigned long long key = packkey(bs, bk * 1024 + t);
    #pragma unroll
    for (int d = 1; d < 64; d <<= 1) {
      unsigned long long o = __shfl_xor(key, d);
      if (o > key) key = o;
    }
    if (lane == 0) s_key[0][w] = key;
  }

  float* ob  = out_box  + (size_t)bc * TDET * 4;
  float* osc = out_sc   + (size_t)bc * TDET;
  int*   opk = out_pick + (size_t)bc * TDET;

  int iter = 0;
  for (; iter < TDET; ++iter) {
    __syncthreads();   // the ONLY barrier per iteration

    // every lane: combine the 16 wave keys (conflict-free read + 4-step butterfly)
    unsigned long long m = s_key[iter & 1][lane & 15];
    #pragma unroll
    for (int d = 1; d < 16; d <<= 1) {
      unsigned long long o = __shfl_xor(m, d);
      if (o > m) m = o;
    }
    float bestS = unpack_score(m);
    if (bestS < CONF_T) break;             // uniform
    int bestJ = (int)(~(unsigned int)m);

    float4 sb = s_box[bestJ];              // broadcast read
    if (t == 0) {
      ob[iter * 4 + 0] = sb.x; ob[iter * 4 + 1] = sb.y;
      ob[iter * 4 + 2] = sb.z; ob[iter * 4 + 3] = sb.w;
      osc[iter] = bestS; opk[iter] = 1;
    }
    float areaS = (sb.z - sb.x) * (sb.w - sb.y);

    // fused update + local argmax
    float bs = NEGF; int bk = 0;
    #pragma unroll
    for (int k = 0; k < 4; ++k) {
      int j = k * 1024 + t;
      if (j < K && rsc[k] != NEGF) {
        if (j == bestJ) {
          rsc[k] = NEGF;
        } else {
          float ltx = fmaxf(sb.x, rbx[k].x);
          float lty = fmaxf(sb.y, rbx[k].y);
          float rbv = fminf(sb.z, rbx[k].z);
          float rby = fminf(sb.w, rbx[k].w);
          float wx = fmaxf(rbv - ltx, 0.0f);
          float wy = fmaxf(rby - lty, 0.0f);
          float inter = wx * wy;
          float uni = (areaS + rar[k]) - inter;
          float iou = (uni > 0.0f) ? (inter / uni) : 0.0f;
          float ns;
          if (iou > 0.5f) ns = NEGF;
          else {
            ns = rsc[k] * expf((-10.0f * iou) * iou);
            if (ns < CONF_T) ns = NEGF;    // pruning: output-equivalent
          }
          rsc[k] = ns;
        }
      }
      if (rsc[k] > bs) { bs = rsc[k]; bk = k; }
    }

    // wave butterfly -> next-parity key slot
    unsigned long long key = packkey(bs, bk * 1024 + t);
    #pragma unroll
    for (int d = 1; d < 64; d <<= 1) {
      unsigned long long o = __shfl_xor(key, d);
      if (o > key) key = o;
    }
    if (lane == 0) s_key[(iter + 1) & 1][w] = key;
  }
  for (int r = iter + t; r < TDET; r += 1024) opk[r] = 0;
}

// ---------------- K5: per-batch compaction + stable top-100 (bitonic) ----------------
__global__ __launch_bounds__(1024) void k_post(
    const float* __restrict__ out_box, const float* __restrict__ out_sc,
    const int* __restrict__ out_pick,
    float* __restrict__ out, int B)
{
  #pragma clang fp contract(off)
  const int b = blockIdx.x;
  const int t = threadIdx.x;

  __shared__ float p_sc[MTOT];
  __shared__ float p_bx[MTOT * 4];
  __shared__ unsigned char p_v[MTOT];
  __shared__ float q_sc[MTOT];
  __shared__ short q_m[MTOT];
  __shared__ int s_wtot[16];
  __shared__ unsigned long long s_key[2048];

  // load class-major entries (m = c*100 + step)
  for (int m = t; m < MTOT; m += 1024) {
    int c = m / TDET, tt = m % TDET;
    int lanebc = b * NCLS + c;
    int pk = out_pick[(size_t)lanebc * TDET + tt];
    p_v[m] = (unsigned char)pk;
    if (pk) {
      p_sc[m] = out_sc[(size_t)lanebc * TDET + tt];
      p_bx[m * 4 + 0] = out_box[((size_t)lanebc * TDET + tt) * 4 + 0];
      p_bx[m * 4 + 1] = out_box[((size_t)lanebc * TDET + tt) * 4 + 1];
      p_bx[m * 4 + 2] = out_box[((size_t)lanebc * TDET + tt) * 4 + 2];
      p_bx[m * 4 + 3] = out_box[((size_t)lanebc * TDET + tt) * 4 + 3];
    } else {
      p_sc[m] = 0.0f;
      p_bx[m * 4 + 0] = 0.0f; p_bx[m * 4 + 1] = 0.0f;
      p_bx[m * 4 + 2] = 0.0f; p_bx[m * 4 + 3] = 0.0f;
    }
  }
  __syncthreads();

  // stable compaction (class-major order preserved)
  int running = 0;
  for (int base = 0; base < MTOT; base += 1024) {
    int m = base + t;
    bool v = (m < MTOT) && p_v[m];
    unsigned long long ball = __ballot(v);
    int lane = t & 63, w = t >> 6;
    if (lane == 0) s_wtot[w] = __popcll(ball);
    __syncthreads();
    int off = 0, tot = 0;
    #pragma unroll
    for (int i = 0; i < 16; ++i) {
      int ci = s_wtot[i];
      if (i < w) off += ci;
      tot += ci;
    }
    if (v) {
      int wpre = __popcll(ball & ((1ull << lane) - 1ull));
      int j = running + off + wpre;
      q_sc[j] = p_sc[m];
      q_m[j] = (short)m;
    }
    running += tot;
    __syncthreads();
  }
  int nv = running;
  bool over = nv > TDET;

  if (over) {
    // keys: inverted so ascending bitonic == (score desc, position asc)
    for (int e = t; e < 2048; e += 1024) {
      unsigned long long kk = 0;
      if (e < nv) {
        unsigned int sb = __float_as_uint(q_sc[e]);   // valid scores > 0
        kk = ((unsigned long long)sb << 32) | (unsigned int)(~e);
      }
      s_key[e] = ~kk;
    }
    for (int kk2 = 2; kk2 <= 2048; kk2 <<= 1) {
      for (int j = kk2 >> 1; j > 0; j >>= 1) {
        __syncthreads();
        int e = ((t & ~(j - 1)) << 1) | (t & (j - 1));
        int q = e | j;
        unsigned long long a = s_key[e], bb = s_key[q];
        bool up = ((e & kk2) == 0);
        bool sw = up ? (a > bb) : (a < bb);
        if (sw) { s_key[e] = bb; s_key[q] = a; }
      }
    }
    __syncthreads();
  }

  // write: [B] valid, [B,100,4] boxes, [B,100] scores, [B,100] classes (all f32)
  int vd = nv < TDET ? nv : TDET;
  int base_box = B;
  int base_sc  = B + B * TDET * 4;
  int base_cl  = base_sc + B * TDET;
  if (t == 0) out[b] = (float)vd;
  if (t < TDET) {
    float sc = 0.0f, cl = -1.0f, b0 = 0.0f, b1 = 0.0f, b2 = 0.0f, b3 = 0.0f;
    int p = -1;
    if (t < nv) p = over ? (int)(unsigned int)s_key[t] : t;
    if (p >= 0) {
      int m = q_m[p];
      sc = q_sc[p];
      cl = (float)(m / TDET);
      b0 = p_bx[m * 4 + 0]; b1 = p_bx[m * 4 + 1];
      b2 = p_bx[m * 4 + 2]; b3 = p_bx[m * 4 + 3];
    }
    int o = b * TDET + t;
    out[base_box + o * 4 + 0] = b0;
    out[base_box + o * 4 + 1] = b1;
    out[base_box + o * 4 + 2] = b2;
    out[base_box + o * 4 + 3] = b3;
    out[base_sc + o] = sc;
    out[base_cl + o] = cl;
  }
}

extern "C" void kernel_launch(void* const* d_in, const int* in_sizes, int n_in,
                              void* d_out, int out_size, void* d_ws, size_t ws_size,
                              hipStream_t stream) {
  const float* pred = (const float*)d_in[0];
  const float* anch = (const float*)d_in[1];
  int N  = in_sizes[1] / 4;       // 49104
  int BN = in_sizes[0] / 20;      // B*N
  int B  = BN / N;                // 4
  int nchunk = (N + 255) / 256;   // 192
  int NBC = B * NCLS;             // 64

  char* ws = (char*)d_ws;
  size_t off = 0;
  float* boxes  = (float*)(ws + off); off += (size_t)BN * 4 * sizeof(float);
  float* candbx = (float*)(ws + off); off += (size_t)NBC * CAP * 4 * sizeof(float);
  float* obox   = (float*)(ws + off); off += (size_t)NBC * TDET * 4 * sizeof(float);
  float* score  = (float*)(ws + off); off += (size_t)BN * sizeof(float);
  float* candsc = (float*)(ws + off); off += (size_t)NBC * CAP * sizeof(float);
  float* osc    = (float*)(ws + off); off += (size_t)NBC * TDET * sizeof(float);
  int*   cls    = (int*)(ws + off);   off += (size_t)BN * sizeof(int);
  int*   counts = (int*)(ws + off);   off += (size_t)NBC * nchunk * sizeof(int);
  int*   offs   = (int*)(ws + off);   off += (size_t)NBC * nchunk * sizeof(int);
  int*   ktot   = (int*)(ws + off);   off += (size_t)NBC * sizeof(int);
  int*   opick  = (int*)(ws + off);   off += (size_t)NBC * TDET * sizeof(int);

  k_decode<<<B * nchunk, 256, 0, stream>>>(pred, anch, boxes, score, cls, counts, N, nchunk);
  k_scan<<<NBC, 256, 0, stream>>>(counts, offs, ktot, nchunk);
  k_scatter<<<B * nchunk, 256, 0, stream>>>(score, cls, boxes, offs, candsc, candbx, N, nchunk);
  k_nms<<<NBC, 1024, 0, stream>>>(candsc, candbx, ktot, obox, osc, opick);
  k_post<<<B, 1024, 0, stream>>>(obox, osc, opick, (float*)d_out, B);
}

// Round 5
// 230.715 us; speedup vs baseline: 1.1276x; 1.1276x over previous
//
#include <hip/hip_runtime.h>
#include <math.h>

#define CONF_T 0.05f
#define NEGF  -1e10f
#define NCLS 16
#define TDET 100
#define CAP 4096
#define MTOT (NCLS*TDET)  // 1600

// ---------------- K1: decode boxes + class/score + per-chunk class counts ----------------
__global__ __launch_bounds__(256) void k_decode(
    const float* __restrict__ pred, const float* __restrict__ anch,
    float* __restrict__ boxes, float* __restrict__ score, int* __restrict__ cls,
    int* __restrict__ counts, int N, int nchunk)
{
  #pragma clang fp contract(off)
  const int b = blockIdx.x / nchunk;
  const int chunk = blockIdx.x % nchunk;
  const int t = threadIdx.x;
  const int n = chunk * 256 + t;

  __shared__ int hist[NCLS];
  if (t < NCLS) hist[t] = 0;
  __syncthreads();

  int v = -1;
  if (n < N) {
    const size_t i = (size_t)b * N + n;
    const float4* p4 = reinterpret_cast<const float4*>(pred + i * 20);
    float4 v0 = p4[0], v1 = p4[1], v2 = p4[2], v3 = p4[3], v4 = p4[4];
    float4 a = reinterpret_cast<const float4*>(anch)[n];  // cx, cy, w, h
    float xx = v0.x * a.z + a.x;
    float yy = v0.y * a.w + a.y;
    float wx = expf(v0.z) * a.z;
    float wy = expf(v0.w) * a.w;
    float hx = 0.5f * wx, hy = 0.5f * wy;
    float4 bx;
    bx.x = xx - hx; bx.y = yy - hy; bx.z = xx + hx; bx.w = yy + hy;
    reinterpret_cast<float4*>(boxes)[i] = bx;

    float lg[NCLS] = {v1.x, v1.y, v1.z, v1.w, v2.x, v2.y, v2.z, v2.w,
                      v3.x, v3.y, v3.z, v3.w, v4.x, v4.y, v4.z, v4.w};
    float best = -1.0f; int bi = 0;
    #pragma unroll
    for (int c = 0; c < NCLS; ++c) {
      float s = 1.0f / (1.0f + expf(-lg[c]));
      if (s > best) { best = s; bi = c; }
    }
    score[i] = best;
    v = (best >= CONF_T) ? bi : -1;
    cls[i] = v;
  }

  int lane = t & 63;
  #pragma unroll
  for (int c = 0; c < NCLS; ++c) {
    unsigned long long bl = __ballot(v == c);
    if (lane == 0 && bl) atomicAdd(&hist[c], __popcll(bl));
  }
  __syncthreads();
  if (t < NCLS) counts[(b * NCLS + t) * nchunk + chunk] = hist[t];
}

// ---------------- K2: per-(b,c) exclusive scan over chunk counts ----------------
__global__ __launch_bounds__(256) void k_scan(
    const int* __restrict__ counts, int* __restrict__ offs, int* __restrict__ ktot,
    int nchunk)
{
  const int bc = blockIdx.x;
  const int t = threadIdx.x;
  __shared__ int c_[256];
  __shared__ int o_[257];
  if (t < nchunk) c_[t] = counts[bc * nchunk + t];
  __syncthreads();
  if (t == 0) {
    int run = 0;
    for (int i = 0; i < nchunk; ++i) { o_[i] = run; run += c_[i]; }
    o_[nchunk] = run;
  }
  __syncthreads();
  if (t < nchunk) offs[bc * nchunk + t] = o_[t];
  if (t == 0) ktot[bc] = o_[nchunk];
}

// ---------------- K3: stable parallel scatter into per-(b,c) candidate lists ----------------
__global__ __launch_bounds__(256) void k_scatter(
    const float* __restrict__ score, const int* __restrict__ cls,
    const float* __restrict__ boxes, const int* __restrict__ offs,
    float* __restrict__ cand_sc, float* __restrict__ cand_bx,
    int N, int nchunk)
{
  const int b = blockIdx.x / nchunk;
  const int chunk = blockIdx.x % nchunk;
  const int t = threadIdx.x;
  const int n = chunk * 256 + t;

  __shared__ int wcnt[4][NCLS];
  int v = (n < N) ? cls[(size_t)b * N + n] : -1;
  int lane = t & 63, w = t >> 6;
  int myrank = 0;
  #pragma unroll
  for (int c = 0; c < NCLS; ++c) {
    unsigned long long bl = __ballot(v == c);
    if (lane == 0) wcnt[w][c] = __popcll(bl);
    if (v == c) myrank = __popcll(bl & ((1ull << lane) - 1ull));
  }
  __syncthreads();
  if (v >= 0) {
    int pre = 0;
    #pragma unroll
    for (int i = 0; i < 4; ++i) if (i < w) pre += wcnt[i][v];
    int pos = offs[(b * NCLS + v) * nchunk + chunk] + pre + myrank;
    if (pos < CAP) {
      int bc = b * NCLS + v;
      cand_sc[(size_t)bc * CAP + pos] = score[(size_t)b * N + n];
      reinterpret_cast<float4*>(cand_bx)[(size_t)bc * CAP + pos] =
          reinterpret_cast<const float4*>(boxes)[(size_t)b * N + n];
    }
  }
}

// ---------------- K4: per-(b,c) soft-NMS, f32/i32 reductions + inter>0 fast path ----------------
__global__ __launch_bounds__(1024) void k_nms(
    const float* __restrict__ cand_sc, const float* __restrict__ cand_bx,
    const int* __restrict__ ktot,
    float* __restrict__ out_box, float* __restrict__ out_sc, int* __restrict__ out_pick)
{
  #pragma clang fp contract(off)
  const int bc = blockIdx.x;
  const int t = threadIdx.x;
  const int lane = t & 63, w = t >> 6;

  __shared__ float4 s_box[CAP];        // 64 KB: all candidate boxes
  __shared__ float  s_wsc[2][16];      // parity-buffered per-wave max score
  __shared__ int    s_wj[2][16];       // parity-buffered per-wave argmin-j at that score

  int K = ktot[bc]; if (K > CAP) K = CAP;

  float  rsc[4];
  float4 rbx[4];
  float  rar[4];
  #pragma unroll
  for (int k = 0; k < 4; ++k) {
    int j = k * 1024 + t;
    if (j < K) {
      rsc[k] = cand_sc[(size_t)bc * CAP + j];
      float4 bb = reinterpret_cast<const float4*>(cand_bx)[(size_t)bc * CAP + j];
      rbx[k] = bb;
      s_box[j] = bb;
      rar[k] = (bb.z - bb.x) * (bb.w - bb.y);   // hoisted areaB (value-identical)
    } else {
      rsc[k] = NEGF;
      rbx[k].x = rbx[k].y = rbx[k].z = rbx[k].w = 0.0f;
      rar[k] = 0.0f;
    }
  }

  // wave-level reduce of (max score, min j at that score) into parity buffer
  auto publish = [&](int par) {
    float bs = rsc[0]; int bk = 0;
    #pragma unroll
    for (int k = 1; k < 4; ++k)
      if (rsc[k] > bs) { bs = rsc[k]; bk = k; }   // strict > => lowest k on ties
    float sm = bs;
    #pragma unroll
    for (int d = 1; d < 64; d <<= 1)
      sm = fmaxf(sm, __shfl_xor(sm, d));
    int jc = 0x7fffffff;
    if (sm >= CONF_T) {                           // wave-uniform
      jc = (bs == sm) ? (bk * 1024 + t) : 0x7fffffff;
      #pragma unroll
      for (int d = 1; d < 64; d <<= 1) {
        int o = __shfl_xor(jc, d);
        jc = (o < jc) ? o : jc;
      }
    }
    if (lane == 0) { s_wsc[par][w] = sm; s_wj[par][w] = jc; }
  };

  publish(0);

  float* ob  = out_box  + (size_t)bc * TDET * 4;
  float* osc = out_sc   + (size_t)bc * TDET;
  int*   opk = out_pick + (size_t)bc * TDET;

  int iter = 0;
  for (; iter < TDET; ++iter) {
    __syncthreads();                   // the only barrier per iteration
    const int par = iter & 1;

    float sv = s_wsc[par][lane & 15];
    int   jw = s_wj[par][lane & 15];
    float sm = sv;
    #pragma unroll
    for (int d = 1; d < 16; d <<= 1)
      sm = fmaxf(sm, __shfl_xor(sm, d));
    if (sm < CONF_T) break;            // uniform: no further picks possible
    int jc = (sv == sm) ? jw : 0x7fffffff;
    #pragma unroll
    for (int d = 1; d < 16; d <<= 1) {
      int o = __shfl_xor(jc, d);
      jc = (o < jc) ? o : jc;
    }
    const int bestJ = jc;
    const float bestS = sm;

    float4 sb = s_box[bestJ];          // broadcast read
    if (t == 0) {
      ob[iter * 4 + 0] = sb.x; ob[iter * 4 + 1] = sb.y;
      ob[iter * 4 + 2] = sb.z; ob[iter * 4 + 3] = sb.w;
      osc[iter] = bestS; opk[iter] = 1;
    }
    float areaS = (sb.z - sb.x) * (sb.w - sb.y);

    #pragma unroll
    for (int k = 0; k < 4; ++k) {
      float s = rsc[k];
      if (s == NEGF) continue;         // dead (also covers j >= K)
      float ltx = fmaxf(sb.x, rbx[k].x);
      float lty = fmaxf(sb.y, rbx[k].y);
      float rbv = fminf(sb.z, rbx[k].z);
      float rby = fminf(sb.w, rbx[k].w);
      float wx = fmaxf(rbv - ltx, 0.0f);
      float wy = fmaxf(rby - lty, 0.0f);
      float inter = wx * wy;
      int j = k * 1024 + t;
      if (j == bestJ) { rsc[k] = NEGF; continue; }
      if (inter > 0.0f) {
        // inter > 0 ==> uni >= inter > 0, so the uni>0 select is vacuous.
        // inter == 0 ==> iou = 0, w = exp(0) = 1, score bit-identical: skip.
        float iou = inter / ((areaS + rar[k]) - inter);
        float ns;
        if (iou > 0.5f) ns = NEGF;
        else {
          ns = s * expf((-10.0f * iou) * iou);
          if (ns < CONF_T) ns = NEGF;  // pruning: output-equivalent
        }
        rsc[k] = ns;
      }
    }

    publish((iter + 1) & 1);
  }
  for (int r = iter + t; r < TDET; r += 1024) opk[r] = 0;
}

// ---------------- K5: per-batch compaction + stable top-100 (bitonic) ----------------
__global__ __launch_bounds__(1024) void k_post(
    const float* __restrict__ out_box, const float* __restrict__ out_sc,
    const int* __restrict__ out_pick,
    float* __restrict__ out, int B)
{
  #pragma clang fp contract(off)
  const int b = blockIdx.x;
  const int t = threadIdx.x;

  __shared__ float p_sc[MTOT];
  __shared__ float p_bx[MTOT * 4];
  __shared__ unsigned char p_v[MTOT];
  __shared__ float q_sc[MTOT];
  __shared__ short q_m[MTOT];
  __shared__ int s_wtot[16];
  __shared__ unsigned long long s_key[2048];

  // load class-major entries (m = c*100 + step)
  for (int m = t; m < MTOT; m += 1024) {
    int c = m / TDET, tt = m % TDET;
    int lanebc = b * NCLS + c;
    int pk = out_pick[(size_t)lanebc * TDET + tt];
    p_v[m] = (unsigned char)pk;
    if (pk) {
      p_sc[m] = out_sc[(size_t)lanebc * TDET + tt];
      p_bx[m * 4 + 0] = out_box[((size_t)lanebc * TDET + tt) * 4 + 0];
      p_bx[m * 4 + 1] = out_box[((size_t)lanebc * TDET + tt) * 4 + 1];
      p_bx[m * 4 + 2] = out_box[((size_t)lanebc * TDET + tt) * 4 + 2];
      p_bx[m * 4 + 3] = out_box[((size_t)lanebc * TDET + tt) * 4 + 3];
    } else {
      p_sc[m] = 0.0f;
      p_bx[m * 4 + 0] = 0.0f; p_bx[m * 4 + 1] = 0.0f;
      p_bx[m * 4 + 2] = 0.0f; p_bx[m * 4 + 3] = 0.0f;
    }
  }
  __syncthreads();

  // stable compaction (class-major order preserved)
  int running = 0;
  for (int base = 0; base < MTOT; base += 1024) {
    int m = base + t;
    bool v = (m < MTOT) && p_v[m];
    unsigned long long ball = __ballot(v);
    int lane = t & 63, w = t >> 6;
    if (lane == 0) s_wtot[w] = __popcll(ball);
    __syncthreads();
    int off = 0, tot = 0;
    #pragma unroll
    for (int i = 0; i < 16; ++i) {
      int ci = s_wtot[i];
      if (i < w) off += ci;
      tot += ci;
    }
    if (v) {
      int wpre = __popcll(ball & ((1ull << lane) - 1ull));
      int j = running + off + wpre;
      q_sc[j] = p_sc[m];
      q_m[j] = (short)m;
    }
    running += tot;
    __syncthreads();
  }
  int nv = running;
  bool over = nv > TDET;

  if (over) {
    // keys: inverted so ascending bitonic == (score desc, position asc)
    for (int e = t; e < 2048; e += 1024) {
      unsigned long long kk = 0;
      if (e < nv) {
        unsigned int sb = __float_as_uint(q_sc[e]);   // valid scores > 0
        kk = ((unsigned long long)sb << 32) | (unsigned int)(~e);
      }
      s_key[e] = ~kk;
    }
    for (int kk2 = 2; kk2 <= 2048; kk2 <<= 1) {
      for (int j = kk2 >> 1; j > 0; j >>= 1) {
        __syncthreads();
        int e = ((t & ~(j - 1)) << 1) | (t & (j - 1));
        int q = e | j;
        unsigned long long a = s_key[e], bb = s_key[q];
        bool up = ((e & kk2) == 0);
        bool sw = up ? (a > bb) : (a < bb);
        if (sw) { s_key[e] = bb; s_key[q] = a; }
      }
    }
    __syncthreads();
  }

  // write: [B] valid, [B,100,4] boxes, [B,100] scores, [B,100] classes (all f32)
  int vd = nv < TDET ? nv : TDET;
  int base_box = B;
  int base_sc  = B + B * TDET * 4;
  int base_cl  = base_sc + B * TDET;
  if (t == 0) out[b] = (float)vd;
  if (t < TDET) {
    float sc = 0.0f, cl = -1.0f, b0 = 0.0f, b1 = 0.0f, b2 = 0.0f, b3 = 0.0f;
    int p = -1;
    if (t < nv) p = over ? (int)(unsigned int)s_key[t] : t;
    if (p >= 0) {
      int m = q_m[p];
      sc = q_sc[p];
      cl = (float)(m / TDET);
      b0 = p_bx[m * 4 + 0]; b1 = p_bx[m * 4 + 1];
      b2 = p_bx[m * 4 + 2]; b3 = p_bx[m * 4 + 3];
    }
    int o = b * TDET + t;
    out[base_box + o * 4 + 0] = b0;
    out[base_box + o * 4 + 1] = b1;
    out[base_box + o * 4 + 2] = b2;
    out[base_box + o * 4 + 3] = b3;
    out[base_sc + o] = sc;
    out[base_cl + o] = cl;
  }
}

extern "C" void kernel_launch(void* const* d_in, const int* in_sizes, int n_in,
                              void* d_out, int out_size, void* d_ws, size_t ws_size,
                              hipStream_t stream) {
  const float* pred = (const float*)d_in[0];
  const float* anch = (const float*)d_in[1];
  int N  = in_sizes[1] / 4;       // 49104
  int BN = in_sizes[0] / 20;      // B*N
  int B  = BN / N;                // 4
  int nchunk = (N + 255) / 256;   // 192
  int NBC = B * NCLS;             // 64

  char* ws = (char*)d_ws;
  size_t off = 0;
  float* boxes  = (float*)(ws + off); off += (size_t)BN * 4 * sizeof(float);
  float* candbx = (float*)(ws + off); off += (size_t)NBC * CAP * 4 * sizeof(float);
  float* obox   = (float*)(ws + off); off += (size_t)NBC * TDET * 4 * sizeof(float);
  float* score  = (float*)(ws + off); off += (size_t)BN * sizeof(float);
  float* candsc = (float*)(ws + off); off += (size_t)NBC * CAP * sizeof(float);
  float* osc    = (float*)(ws + off); off += (size_t)NBC * TDET * sizeof(float);
  int*   cls    = (int*)(ws + off);   off += (size_t)BN * sizeof(int);
  int*   counts = (int*)(ws + off);   off += (size_t)NBC * nchunk * sizeof(int);
  int*   offs   = (int*)(ws + off);   off += (size_t)NBC * nchunk * sizeof(int);
  int*   ktot   = (int*)(ws + off);   off += (size_t)NBC * sizeof(int);
  int*   opick  = (int*)(ws + off);   off += (size_t)NBC * TDET * sizeof(int);

  k_decode<<<B * nchunk, 256, 0, stream>>>(pred, anch, boxes, score, cls, counts, N, nchunk);
  k_scan<<<NBC, 256, 0, stream>>>(counts, offs, ktot, nchunk);
  k_scatter<<<B * nchunk, 256, 0, stream>>>(score, cls, boxes, offs, candsc, candbx, N, nchunk);
  k_nms<<<NBC, 1024, 0, stream>>>(candsc, candbx, ktot, obox, osc, opick);
  k_post<<<B, 1024, 0, stream>>>(obox, osc, opick, (float*)d_out, B);
}